// Round 3
// baseline (654.233 us; speedup 1.0000x reference)
//
#include <hip/hip_runtime.h>

// ---------------------------------------------------------------------------
// Fused attention: Q/K/V = x@W^T + b ; RoPE(Q,K) ; softmax(QK^T/sqrt(D)) @ V
// B=32 S=1024 D=768.  fp16 MFMA (16x16x32), fp32 accumulate.
// R6: alias-disjoint double buffering. Theory: SIInsertWaitcnts orders any
//     ds_read against outstanding global_load_lds (LDS-DMA) at LDS-OBJECT
//     granularity; a single sA[2][...] array made the compiler insert its own
//     vmcnt waits before every phase's reads, nullifying R4/R5's counted-vmcnt
//     pipeline (R3/R4/R5 all stuck at 26-28% MfmaUtil).  Now: 4 separate
//     __shared__ arrays; step t reads ONLY {A_cur,B_cur}, DMAs ONLY into
//     {A_oth,B_oth} -> disjoint objects -> no compiler waits.  One vmcnt(0) +
//     one raw asm s_barrier per K-step, after the 64-MFMA cluster; stages
//     issue at step start (T14).  Compiler handles ds_read->MFMA lgkm waits
//     fine-grained (m97), giving wave-staggered LDS||MFMA overlap.
// ---------------------------------------------------------------------------

typedef __attribute__((ext_vector_type(8))) _Float16 f16x8;
typedef __attribute__((ext_vector_type(4))) float    f32x4;

__device__ __forceinline__ unsigned short f2h(float f) {
    _Float16 h = (_Float16)f;
    return __builtin_bit_cast(unsigned short, h);
}
__device__ __forceinline__ float h2f(unsigned short u) {
    return (float)__builtin_bit_cast(_Float16, u);
}

__device__ __forceinline__ void async_ld16(const void* g, void* l) {
    __builtin_amdgcn_global_load_lds(
        (const __attribute__((address_space(1))) void*)g,
        (__attribute__((address_space(3))) void*)l, 16, 0, 0);
}

// MODE 0: QK proj: A=x[32768x768], B=Wqk[1536x768]; bias+RoPE; Q*=scale. grid 768
// MODE 1: V^T:    A=Wv[768x768],  B=x[32768x768]; bias[row]; out [b][d][s]. grid 384
// MODE 2: scores: A=Q[b], B=K[b], fp16 out [q][k]. grid 512
// MODE 3: PV:     A=P[b], B=Vt[b], fp32 out [q][d]. grid 384
template<int MODE, int KDIM, int LDA, int LDB>
__global__ __launch_bounds__(512, 2)
void gemm_bt(const unsigned short* __restrict__ A,
             const unsigned short* __restrict__ B,
             void* __restrict__ C0, void* __restrict__ C1,
             const float* __restrict__ bias0,
             const float* __restrict__ bias1,
             float scale)
{
    // Four SEPARATE LDS objects (alias-analysis-disjoint).  [256 rows][64
    // halfs each]; 16B-chunk p of row r holds logical k-chunk p^(r&7):
    // staging swizzles the GLOBAL source, LDS stays linear.
    __shared__ __align__(16) unsigned short sA0[256 * 64];
    __shared__ __align__(16) unsigned short sA1[256 * 64];
    __shared__ __align__(16) unsigned short sB0[256 * 64];
    __shared__ __align__(16) unsigned short sB1[256 * 64];

    const int tid  = threadIdx.x;
    const int lane = tid & 63;
    const int wave = tid >> 6;          // 0..7
    const int wm   = wave >> 2;         // 0..1  (M half)
    const int wn   = wave & 3;          // 0..3  (N quarter)
    const int wrow = wm * 128;
    const int wcol = wn * 64;
    const int quad = lane >> 4;
    const int l15  = lane & 15;

    // --- XCD-chunked decode: blockIdx%8 ~ XCD; each XCD gets a contiguous
    //     panel-sharing run so the shared operand stays in its 4 MiB L2. ---
    const int xcd = blockIdx.x & 7;
    const int bi  = blockIdx.x >> 3;
    int m0, n0, z = 0;
    if constexpr (MODE == 0) {          // 128 m-tiles x 6 n-tiles
        m0 = (xcd * 16 + bi / 6) * 256;  n0 = (bi % 6) * 256;
    } else if constexpr (MODE == 1) {   // 3 m-tiles x 128 n-tiles
        n0 = (xcd * 16 + bi / 3) * 256;  m0 = (bi % 3) * 256;
    } else if constexpr (MODE == 2) {   // 32 z x (4x4 tiles)
        z = xcd * 4 + bi / 16; const int t = bi % 16;
        m0 = (t >> 2) * 256; n0 = (t & 3) * 256;
    } else {                            // 32 z x (4x3 tiles)
        z = xcd * 4 + bi / 12; const int t = bi % 12;
        m0 = (t / 3) * 256;  n0 = (t % 3) * 256;
    }

    const unsigned short* Ab = A;
    const unsigned short* Bb = B;
    if constexpr (MODE == 2) { Ab += (size_t)z * 786432;  Bb += (size_t)z * 786432; }
    if constexpr (MODE == 3) { Ab += (size_t)z * 1048576; Bb += (size_t)z * 786432; }

    // Staging: 4 global_load_lds per 256-row matrix tile (64 rows each).
    const int srow = tid >> 3;                       // 0..63
    const int sk   = ((tid & 7) ^ (srow & 7)) * 8;   // swizzled logical k-chunk
    const int sdst = (tid & 7) * 8;

    auto stageA = [&](unsigned short* dst, int kt) {
        #pragma unroll
        for (int g = 0; g < 4; ++g)
            async_ld16(Ab + (size_t)(m0 + g * 64 + srow) * LDA + kt + sk,
                       &dst[(g * 64 + srow) * 64 + sdst]);
    };
    auto stageB = [&](unsigned short* dst, int kt) {
        #pragma unroll
        for (int g = 0; g < 4; ++g)
            async_ld16(Bb + (size_t)(n0 + g * 64 + srow) * LDB + kt + sk,
                       &dst[(g * 64 + srow) * 64 + sdst]);
    };

    f32x4 acc[8][4] = {};

    constexpr int NT = KDIM / 64;   // 12 or 16 (even)

    // K-step body: reads ONLY Ac/Bc, DMAs ONLY into Ao/Bo (disjoint objects).
    auto kstep = [&](const unsigned short* Ac, const unsigned short* Bc,
                     unsigned short* Ao, unsigned short* Bo, int t)
        __attribute__((always_inline))
    {
        // Issue next-tile stages first: full K-step of latency headroom.
        if (t + 1 < NT) { stageA(Ao, (t + 1) * 64); stageB(Bo, (t + 1) * 64); }

        f16x8 a[8][2], b[4][2];
        #pragma unroll
        for (int ni = 0; ni < 4; ++ni) {
            const int r = wcol + ni * 16 + l15;
            const int x = r & 7;
            b[ni][0] = *(const f16x8*)&Bc[r * 64 + ((quad       ^ x) << 3)];
            b[ni][1] = *(const f16x8*)&Bc[r * 64 + (((4 + quad) ^ x) << 3)];
        }
        #pragma unroll
        for (int mi = 0; mi < 8; ++mi) {
            const int r = wrow + mi * 16 + l15;
            const int x = r & 7;
            a[mi][0] = *(const f16x8*)&Ac[r * 64 + ((quad       ^ x) << 3)];
            a[mi][1] = *(const f16x8*)&Ac[r * 64 + (((4 + quad) ^ x) << 3)];
        }

        __builtin_amdgcn_s_setprio(1);
        #pragma unroll
        for (int mi = 0; mi < 8; ++mi)
            #pragma unroll
            for (int ni = 0; ni < 4; ++ni) {
                acc[mi][ni] = __builtin_amdgcn_mfma_f32_16x16x32_f16(
                    a[mi][0], b[ni][0], acc[mi][ni], 0, 0, 0);
                acc[mi][ni] = __builtin_amdgcn_mfma_f32_16x16x32_f16(
                    a[mi][1], b[ni][1], acc[mi][ni], 0, 0, 0);
            }
        __builtin_amdgcn_s_setprio(0);

        // Per-wave: own reads already consumed; own DMAs (tile t+1) drained.
        // Barrier: all waves' reads of cur done (next step DMAs into cur) and
        // all waves' DMAs into oth landed (next step reads oth).
        asm volatile("s_waitcnt vmcnt(0)" ::: "memory");
        asm volatile("s_barrier" ::: "memory");
    };

    // Prologue: tile 0 -> {sA0,sB0}.
    stageA(sA0, 0); stageB(sB0, 0);
    asm volatile("s_waitcnt vmcnt(0)" ::: "memory");
    asm volatile("s_barrier" ::: "memory");

    for (int t = 0; t < NT; t += 2) {
        kstep(sA0, sB0, sA1, sB1, t);
        kstep(sA1, sB1, sA0, sB0, t + 1);
    }

    // Epilogue. C/D layout: col = lane&15, row = quad*4 + reg  [m89-verified]
    const bool evenlane = (l15 & 1) == 0;

    float invf[4];
    if constexpr (MODE == 0) {
        #pragma unroll
        for (int ni = 0; ni < 4; ++ni) {
            int col = n0 + wcol + ni * 16 + l15;
            if (col >= 768) col -= 768;
            // inv_freq[i] = 2^(-i * 2*log2(10000)/768)
            invf[ni] = exp2f((float)(col >> 1) * -0.03460341765507773f);
        }
    }

    #pragma unroll
    for (int mi = 0; mi < 8; ++mi) {
        const int rowoff = mi * 16;
        #pragma unroll
        for (int ni = 0; ni < 4; ++ni) {
            #pragma unroll
            for (int reg = 0; reg < 4; ++reg) {
                const int grow = m0 + wrow + rowoff + quad * 4 + reg;
                const int gcol = n0 + wcol + ni * 16 + l15;
                float v = acc[mi][ni][reg];
                if constexpr (MODE == 0) {
                    const bool isQ = gcol < 768;          // block-uniform
                    const int  col = isQ ? gcol : gcol - 768;
                    v += isQ ? bias0[col] : bias1[col];
                    const float other = __shfl_xor(v, 1); // RoPE partner column
                    const int   s     = grow & 1023;
                    const float ang   = (float)s * invf[ni];
                    float sn, cs;
                    __sincosf(ang, &sn, &cs);
                    float r = (col & 1) ? fmaf(other, sn, v * cs)
                                        : fmaf(v, cs, -(other * sn));
                    if (isQ) r *= scale;
                    const unsigned short h = f2h(r);
                    const unsigned int packed =
                        (unsigned int)h | (__shfl_xor((unsigned int)h, 1) << 16);
                    if (evenlane) {
                        unsigned short* dst = (unsigned short*)(isQ ? C0 : C1);
                        *(unsigned int*)(dst + (size_t)grow * 768 + col) = packed;
                    }
                } else if constexpr (MODE == 1) {
                    v += bias0[grow];  // output feature = row (d)
                    const unsigned short h = f2h(v);
                    const unsigned int packed =
                        (unsigned int)h | (__shfl_xor((unsigned int)h, 1) << 16);
                    if (evenlane) {
                        const int b = gcol >> 10, s = gcol & 1023;
                        *(unsigned int*)((unsigned short*)C0 + (size_t)b * (768 * 1024)
                                         + (size_t)grow * 1024 + s) = packed;
                    }
                } else if constexpr (MODE == 2) {
                    const unsigned short h = f2h(v);
                    const unsigned int packed =
                        (unsigned int)h | (__shfl_xor((unsigned int)h, 1) << 16);
                    if (evenlane) {
                        *(unsigned int*)((unsigned short*)C0 + (size_t)z * 1048576
                                         + (size_t)grow * 1024 + gcol) = packed;
                    }
                } else {
                    const float vo = __shfl_xor(v, 1);
                    if (evenlane) {
                        float2 pk; pk.x = v; pk.y = vo;
                        *(float2*)(((float*)C0) + (size_t)z * 786432
                                   + (size_t)grow * 768 + gcol) = pk;
                    }
                }
            }
        }
    }
}

__global__ __launch_bounds__(256)
void softmax_rows(const unsigned short* __restrict__ S, unsigned short* __restrict__ P)
{
    const int row = blockIdx.x;           // 32*1024 rows
    const int tid = threadIdx.x;
    const ushort4 u = ((const ushort4*)(S + (size_t)row * 1024))[tid];
    const float v0 = h2f(u.x), v1 = h2f(u.y), v2 = h2f(u.z), v3 = h2f(u.w);

    float m = fmaxf(fmaxf(v0, v1), fmaxf(v2, v3));
    #pragma unroll
    for (int o = 1; o < 64; o <<= 1) m = fmaxf(m, __shfl_xor(m, o));
    __shared__ float redm[4];
    __shared__ float reds[4];
    const int wave = tid >> 6, lane = tid & 63;
    if (lane == 0) redm[wave] = m;
    __syncthreads();
    m = fmaxf(fmaxf(redm[0], redm[1]), fmaxf(redm[2], redm[3]));

    const float e0 = __expf(v0 - m), e1 = __expf(v1 - m);
    const float e2 = __expf(v2 - m), e3 = __expf(v3 - m);
    float sum = e0 + e1 + e2 + e3;
    #pragma unroll
    for (int o = 1; o < 64; o <<= 1) sum += __shfl_xor(sum, o);
    if (lane == 0) reds[wave] = sum;
    __syncthreads();
    sum = reds[0] + reds[1] + reds[2] + reds[3];
    const float inv = 1.0f / sum;

    ushort4 o4;
    o4.x = f2h(e0 * inv); o4.y = f2h(e1 * inv);
    o4.z = f2h(e2 * inv); o4.w = f2h(e3 * inv);
    ((ushort4*)(P + (size_t)row * 1024))[tid] = o4;
}

__global__ void cvt_f32_f16(const float4* __restrict__ in,
                            ushort4* __restrict__ out, int n4)
{
    int i = blockIdx.x * 256 + threadIdx.x;
    const int stride = gridDim.x * 256;
    for (; i < n4; i += stride) {
        const float4 v = in[i];
        ushort4 o;
        o.x = f2h(v.x); o.y = f2h(v.y); o.z = f2h(v.z); o.w = f2h(v.w);
        out[i] = o;
    }
}

extern "C" void kernel_launch(void* const* d_in, const int* in_sizes, int n_in,
                              void* d_out, int out_size, void* d_ws, size_t ws_size,
                              hipStream_t stream)
{
    const float* x  = (const float*)d_in[0];
    const float* Wq = (const float*)d_in[1];
    const float* bq = (const float*)d_in[2];
    const float* Wk = (const float*)d_in[3];
    const float* bk = (const float*)d_in[4];
    const float* Wv = (const float*)d_in[5];
    const float* bv = (const float*)d_in[6];
    float* out = (float*)d_out;

    // Workspace layout (bytes). High-water: ~272 MB.
    char* ws = (char*)d_ws;
    unsigned short* xh  = (unsigned short*)(ws + 0);          // 48 MB fp16 x
    unsigned short* wqk = (unsigned short*)(ws + 50331648);   // Wq||Wk [1536][768]
    unsigned short* wvh = (unsigned short*)(ws + 52690944);
    unsigned short* Qh  = (unsigned short*)(ws + 53870592);   // 48 MB
    unsigned short* Kh  = (unsigned short*)(ws + 104202240);  // 48 MB
    unsigned short* Vt  = (unsigned short*)(ws + 154533888);  // 48 MB  [b][d][s]
    unsigned short* Sc  = (unsigned short*)(ws + 204865536);  // 64 MB fp16 scores
    unsigned short* Ph  = (unsigned short*)(ws + 0);          // 64 MB (x/W dead)

    // 1) fp32 -> fp16 conversions
    cvt_f32_f16<<<4096, 256, 0, stream>>>((const float4*)x,  (ushort4*)xh, 25165824 / 4);
    cvt_f32_f16<<<576,  256, 0, stream>>>((const float4*)Wq, (ushort4*)wqk, 589824 / 4);
    cvt_f32_f16<<<576,  256, 0, stream>>>((const float4*)Wk, (ushort4*)(wqk + 589824), 589824 / 4);
    cvt_f32_f16<<<576,  256, 0, stream>>>((const float4*)Wv, (ushort4*)wvh, 589824 / 4);

    const float qscale = 0.03608439182435161f;  // 1/sqrt(768), folded into Q

    // 2) Q,K = rope(x@Wqk^T + b) (Q scaled); fused over concatenated Wqk
    gemm_bt<0, 768, 768, 768><<<768, 512, 0, stream>>>(
        xh, wqk, Qh, Kh, bq, bk, qscale);
    // 3) V^T[b][d][s] via swapped operands
    gemm_bt<1, 768, 768, 768><<<384, 512, 0, stream>>>(
        wvh, xh, Vt, nullptr, bv, nullptr, 1.0f);
    // 4) scores[b] = Q[b] @ K[b]^T  (scale already in Q), fp16 out
    gemm_bt<2, 768, 768, 768><<<512, 512, 0, stream>>>(
        Qh, Kh, Sc, nullptr, nullptr, nullptr, 1.0f);
    // 5) P = softmax(scores) as fp16
    softmax_rows<<<32768, 256, 0, stream>>>(Sc, Ph);
    // 6) out[b] = P[b] @ V[b] == gemm_bt(P, V^T)
    gemm_bt<3, 1024, 1024, 1024><<<384, 512, 0, stream>>>(
        Ph, Vt, out, nullptr, nullptr, nullptr, 1.0f);
}

// Round 4
// 520.218 us; speedup vs baseline: 1.2576x; 1.2576x over previous
//
#include <hip/hip_runtime.h>

// ---------------------------------------------------------------------------
// Fused attention: Q/K/V = x@W^T + b ; RoPE(Q,K) ; softmax(QK^T/sqrt(D)) @ V
// B=32 S=1024 D=768.  fp16 MFMA (16x16x32), fp32 accumulate.
// R7: free-running K-step.  R5 arithmetic showed the 26% wall = per-phase
//     all-wave barriers alternating {LDS burst ~700cy} / {MFMA burst 515cy}
//     CU-wide (4 phases x 1400cy = 7840cy measured, MFMA frac = 26% exactly).
//     Barriers are only needed for DMA-vs-read ordering, which disjoint
//     double buffers solve with ONE barrier per K-step:
//       stage(t+1 -> other bufs) ; read B frags ; per-mi {read A pair, 8 MFMA}
//       ... vmcnt(0) ; s_barrier ; swap.
//     Waves free-run within the step -> LDS service overlaps other waves'
//     MFMA.  R6's spill fixed: only 2 A-frags live (not 16); launch_bounds
//     (512,1) lifts the 128-VGPR allocator cap (LDS=128KiB already caps at
//     1 block/CU so occupancy is unchanged).
// ---------------------------------------------------------------------------

typedef __attribute__((ext_vector_type(8))) _Float16 f16x8;
typedef __attribute__((ext_vector_type(4))) float    f32x4;

__device__ __forceinline__ unsigned short f2h(float f) {
    _Float16 h = (_Float16)f;
    return __builtin_bit_cast(unsigned short, h);
}
__device__ __forceinline__ float h2f(unsigned short u) {
    return (float)__builtin_bit_cast(_Float16, u);
}

__device__ __forceinline__ void async_ld16(const void* g, void* l) {
    __builtin_amdgcn_global_load_lds(
        (const __attribute__((address_space(1))) void*)g,
        (__attribute__((address_space(3))) void*)l, 16, 0, 0);
}

// MODE 0: QK proj: A=x[32768x768], B=Wqk[1536x768]; bias+RoPE; Q*=scale. grid 768
// MODE 1: V^T:    A=Wv[768x768],  B=x[32768x768]; bias[row]; out [b][d][s]. grid 384
// MODE 2: scores: A=Q[b], B=K[b], fp16 out [q][k]. grid 512
// MODE 3: PV:     A=P[b], B=Vt[b], fp32 out [q][d]. grid 384
template<int MODE, int KDIM, int LDA, int LDB>
__global__ __launch_bounds__(512, 1)
void gemm_bt(const unsigned short* __restrict__ A,
             const unsigned short* __restrict__ B,
             void* __restrict__ C0, void* __restrict__ C1,
             const float* __restrict__ bias0,
             const float* __restrict__ bias1,
             float scale)
{
    // Four SEPARATE LDS objects (alias-analysis-disjoint).  [256 rows][64
    // halfs each]; 16B-chunk p of row r holds logical k-chunk p^(r&7):
    // staging swizzles the GLOBAL source, LDS stays linear.
    __shared__ __align__(16) unsigned short sA0[256 * 64];
    __shared__ __align__(16) unsigned short sA1[256 * 64];
    __shared__ __align__(16) unsigned short sB0[256 * 64];
    __shared__ __align__(16) unsigned short sB1[256 * 64];

    const int tid  = threadIdx.x;
    const int lane = tid & 63;
    const int wave = tid >> 6;          // 0..7
    const int wm   = wave >> 2;         // 0..1  (M half)
    const int wn   = wave & 3;          // 0..3  (N quarter)
    const int wrow = wm * 128;
    const int wcol = wn * 64;
    const int quad = lane >> 4;
    const int l15  = lane & 15;

    // --- XCD-chunked decode: blockIdx%8 ~ XCD; each XCD gets a contiguous
    //     panel-sharing run so the shared operand stays in its 4 MiB L2. ---
    const int xcd = blockIdx.x & 7;
    const int bi  = blockIdx.x >> 3;
    int m0, n0, z = 0;
    if constexpr (MODE == 0) {          // 128 m-tiles x 6 n-tiles
        m0 = (xcd * 16 + bi / 6) * 256;  n0 = (bi % 6) * 256;
    } else if constexpr (MODE == 1) {   // 3 m-tiles x 128 n-tiles
        n0 = (xcd * 16 + bi / 3) * 256;  m0 = (bi % 3) * 256;
    } else if constexpr (MODE == 2) {   // 32 z x (4x4 tiles)
        z = xcd * 4 + bi / 16; const int t = bi % 16;
        m0 = (t >> 2) * 256; n0 = (t & 3) * 256;
    } else {                            // 32 z x (4x3 tiles)
        z = xcd * 4 + bi / 12; const int t = bi % 12;
        m0 = (t / 3) * 256;  n0 = (t % 3) * 256;
    }

    const unsigned short* Ab = A;
    const unsigned short* Bb = B;
    if constexpr (MODE == 2) { Ab += (size_t)z * 786432;  Bb += (size_t)z * 786432; }
    if constexpr (MODE == 3) { Ab += (size_t)z * 1048576; Bb += (size_t)z * 786432; }

    // Staging: 4 global_load_lds per 256-row matrix tile (64 rows each).
    const int srow = tid >> 3;                       // 0..63
    const int sk   = ((tid & 7) ^ (srow & 7)) * 8;   // swizzled logical k-chunk
    const int sdst = (tid & 7) * 8;

    auto stageA = [&](unsigned short* dst, int kt) {
        #pragma unroll
        for (int g = 0; g < 4; ++g)
            async_ld16(Ab + (size_t)(m0 + g * 64 + srow) * LDA + kt + sk,
                       &dst[(g * 64 + srow) * 64 + sdst]);
    };
    auto stageB = [&](unsigned short* dst, int kt) {
        #pragma unroll
        for (int g = 0; g < 4; ++g)
            async_ld16(Bb + (size_t)(n0 + g * 64 + srow) * LDB + kt + sk,
                       &dst[(g * 64 + srow) * 64 + sdst]);
    };

    f32x4 acc[8][4] = {};

    constexpr int NT = KDIM / 64;   // 12 or 16 (even)

    // Free-running K-step: reads ONLY Ac/Bc, DMAs ONLY into Ao/Bo (disjoint
    // objects).  NO intra-step barriers: waves drift, LDS service of one
    // wave overlaps MFMA of others.  Compiler inserts fine-grained lgkmcnt
    // for ds_read->MFMA deps (m97-verified near-optimal).
    auto kstep = [&](const unsigned short* Ac, const unsigned short* Bc,
                     unsigned short* Ao, unsigned short* Bo, int t)
    {
        // Issue next-tile stages first: full K-step of latency headroom (T14).
        if (t + 1 < NT) { stageA(Ao, (t + 1) * 64); stageB(Bo, (t + 1) * 64); }

        f16x8 b[4][2];
        #pragma unroll
        for (int ni = 0; ni < 4; ++ni) {
            const int r = wcol + ni * 16 + l15;
            const int x = r & 7;
            b[ni][0] = *(const f16x8*)&Bc[r * 64 + ((quad       ^ x) << 3)];
            b[ni][1] = *(const f16x8*)&Bc[r * 64 + (((4 + quad) ^ x) << 3)];
        }
        #pragma unroll
        for (int mi = 0; mi < 8; ++mi) {
            const int r = wrow + mi * 16 + l15;
            const int x = r & 7;
            const f16x8 a0 = *(const f16x8*)&Ac[r * 64 + ((quad       ^ x) << 3)];
            const f16x8 a1 = *(const f16x8*)&Ac[r * 64 + (((4 + quad) ^ x) << 3)];
            #pragma unroll
            for (int ni = 0; ni < 4; ++ni) {
                acc[mi][ni] = __builtin_amdgcn_mfma_f32_16x16x32_f16(
                    a0, b[ni][0], acc[mi][ni], 0, 0, 0);
                acc[mi][ni] = __builtin_amdgcn_mfma_f32_16x16x32_f16(
                    a1, b[ni][1], acc[mi][ni], 0, 0, 0);
            }
        }

        // Own reads consumed (MFMA deps forced lgkm waits); own DMAs drained
        // (they had the whole step).  Barrier: everyone's reads of cur done
        // (next step DMAs into cur) and everyone's DMAs into oth landed
        // (next step reads oth).  ONE barrier + ONE vmcnt per K-step.
        asm volatile("s_waitcnt vmcnt(0)" ::: "memory");
        asm volatile("s_barrier" ::: "memory");
    };

    // Prologue: tile 0 -> {sA0,sB0}.
    stageA(sA0, 0); stageB(sB0, 0);
    asm volatile("s_waitcnt vmcnt(0)" ::: "memory");
    asm volatile("s_barrier" ::: "memory");

    for (int t = 0; t < NT; t += 2) {
        kstep(sA0, sB0, sA1, sB1, t);
        kstep(sA1, sB1, sA0, sB0, t + 1);
    }

    // Epilogue. C/D layout: col = lane&15, row = quad*4 + reg  [m89-verified]
    const bool evenlane = (l15 & 1) == 0;

    float invf[4];
    if constexpr (MODE == 0) {
        #pragma unroll
        for (int ni = 0; ni < 4; ++ni) {
            int col = n0 + wcol + ni * 16 + l15;
            if (col >= 768) col -= 768;
            // inv_freq[i] = 2^(-i * 2*log2(10000)/768)
            invf[ni] = exp2f((float)(col >> 1) * -0.03460341765507773f);
        }
    }

    #pragma unroll
    for (int mi = 0; mi < 8; ++mi) {
        const int rowoff = mi * 16;
        #pragma unroll
        for (int ni = 0; ni < 4; ++ni) {
            #pragma unroll
            for (int reg = 0; reg < 4; ++reg) {
                const int grow = m0 + wrow + rowoff + quad * 4 + reg;
                const int gcol = n0 + wcol + ni * 16 + l15;
                float v = acc[mi][ni][reg];
                if constexpr (MODE == 0) {
                    const bool isQ = gcol < 768;          // block-uniform
                    const int  col = isQ ? gcol : gcol - 768;
                    v += isQ ? bias0[col] : bias1[col];
                    const float other = __shfl_xor(v, 1); // RoPE partner column
                    const int   s     = grow & 1023;
                    const float ang   = (float)s * invf[ni];
                    float sn, cs;
                    __sincosf(ang, &sn, &cs);
                    float r = (col & 1) ? fmaf(other, sn, v * cs)
                                        : fmaf(v, cs, -(other * sn));
                    if (isQ) r *= scale;
                    const unsigned short h = f2h(r);
                    const unsigned int packed =
                        (unsigned int)h | (__shfl_xor((unsigned int)h, 1) << 16);
                    if (evenlane) {
                        unsigned short* dst = (unsigned short*)(isQ ? C0 : C1);
                        *(unsigned int*)(dst + (size_t)grow * 768 + col) = packed;
                    }
                } else if constexpr (MODE == 1) {
                    v += bias0[grow];  // output feature = row (d)
                    const unsigned short h = f2h(v);
                    const unsigned int packed =
                        (unsigned int)h | (__shfl_xor((unsigned int)h, 1) << 16);
                    if (evenlane) {
                        const int b = gcol >> 10, s = gcol & 1023;
                        *(unsigned int*)((unsigned short*)C0 + (size_t)b * (768 * 1024)
                                         + (size_t)grow * 1024 + s) = packed;
                    }
                } else if constexpr (MODE == 2) {
                    const unsigned short h = f2h(v);
                    const unsigned int packed =
                        (unsigned int)h | (__shfl_xor((unsigned int)h, 1) << 16);
                    if (evenlane) {
                        *(unsigned int*)((unsigned short*)C0 + (size_t)z * 1048576
                                         + (size_t)grow * 1024 + gcol) = packed;
                    }
                } else {
                    const float vo = __shfl_xor(v, 1);
                    if (evenlane) {
                        float2 pk; pk.x = v; pk.y = vo;
                        *(float2*)(((float*)C0) + (size_t)z * 786432
                                   + (size_t)grow * 768 + gcol) = pk;
                    }
                }
            }
        }
    }
}

__global__ __launch_bounds__(256)
void softmax_rows(const unsigned short* __restrict__ S, unsigned short* __restrict__ P)
{
    const int row = blockIdx.x;           // 32*1024 rows
    const int tid = threadIdx.x;
    const ushort4 u = ((const ushort4*)(S + (size_t)row * 1024))[tid];
    const float v0 = h2f(u.x), v1 = h2f(u.y), v2 = h2f(u.z), v3 = h2f(u.w);

    float m = fmaxf(fmaxf(v0, v1), fmaxf(v2, v3));
    #pragma unroll
    for (int o = 1; o < 64; o <<= 1) m = fmaxf(m, __shfl_xor(m, o));
    __shared__ float redm[4];
    __shared__ float reds[4];
    const int wave = tid >> 6, lane = tid & 63;
    if (lane == 0) redm[wave] = m;
    __syncthreads();
    m = fmaxf(fmaxf(redm[0], redm[1]), fmaxf(redm[2], redm[3]));

    const float e0 = __expf(v0 - m), e1 = __expf(v1 - m);
    const float e2 = __expf(v2 - m), e3 = __expf(v3 - m);
    float sum = e0 + e1 + e2 + e3;
    #pragma unroll
    for (int o = 1; o < 64; o <<= 1) sum += __shfl_xor(sum, o);
    if (lane == 0) reds[wave] = sum;
    __syncthreads();
    sum = reds[0] + reds[1] + reds[2] + reds[3];
    const float inv = 1.0f / sum;

    ushort4 o4;
    o4.x = f2h(e0 * inv); o4.y = f2h(e1 * inv);
    o4.z = f2h(e2 * inv); o4.w = f2h(e3 * inv);
    ((ushort4*)(P + (size_t)row * 1024))[tid] = o4;
}

__global__ void cvt_f32_f16(const float4* __restrict__ in,
                            ushort4* __restrict__ out, int n4)
{
    int i = blockIdx.x * 256 + threadIdx.x;
    const int stride = gridDim.x * 256;
    for (; i < n4; i += stride) {
        const float4 v = in[i];
        ushort4 o;
        o.x = f2h(v.x); o.y = f2h(v.y); o.z = f2h(v.z); o.w = f2h(v.w);
        out[i] = o;
    }
}

extern "C" void kernel_launch(void* const* d_in, const int* in_sizes, int n_in,
                              void* d_out, int out_size, void* d_ws, size_t ws_size,
                              hipStream_t stream)
{
    const float* x  = (const float*)d_in[0];
    const float* Wq = (const float*)d_in[1];
    const float* bq = (const float*)d_in[2];
    const float* Wk = (const float*)d_in[3];
    const float* bk = (const float*)d_in[4];
    const float* Wv = (const float*)d_in[5];
    const float* bv = (const float*)d_in[6];
    float* out = (float*)d_out;

    // Workspace layout (bytes). High-water: ~272 MB.
    char* ws = (char*)d_ws;
    unsigned short* xh  = (unsigned short*)(ws + 0);          // 48 MB fp16 x
    unsigned short* wqk = (unsigned short*)(ws + 50331648);   // Wq||Wk [1536][768]
    unsigned short* wvh = (unsigned short*)(ws + 52690944);
    unsigned short* Qh  = (unsigned short*)(ws + 53870592);   // 48 MB
    unsigned short* Kh  = (unsigned short*)(ws + 104202240);  // 48 MB
    unsigned short* Vt  = (unsigned short*)(ws + 154533888);  // 48 MB  [b][d][s]
    unsigned short* Sc  = (unsigned short*)(ws + 204865536);  // 64 MB fp16 scores
    unsigned short* Ph  = (unsigned short*)(ws + 0);          // 64 MB (x/W dead)

    // 1) fp32 -> fp16 conversions
    cvt_f32_f16<<<4096, 256, 0, stream>>>((const float4*)x,  (ushort4*)xh, 25165824 / 4);
    cvt_f32_f16<<<576,  256, 0, stream>>>((const float4*)Wq, (ushort4*)wqk, 589824 / 4);
    cvt_f32_f16<<<576,  256, 0, stream>>>((const float4*)Wk, (ushort4*)(wqk + 589824), 589824 / 4);
    cvt_f32_f16<<<576,  256, 0, stream>>>((const float4*)Wv, (ushort4*)wvh, 589824 / 4);

    const float qscale = 0.03608439182435161f;  // 1/sqrt(768), folded into Q

    // 2) Q,K = rope(x@Wqk^T + b) (Q scaled); fused over concatenated Wqk
    gemm_bt<0, 768, 768, 768><<<768, 512, 0, stream>>>(
        xh, wqk, Qh, Kh, bq, bk, qscale);
    // 3) V^T[b][d][s] via swapped operands
    gemm_bt<1, 768, 768, 768><<<384, 512, 0, stream>>>(
        wvh, xh, Vt, nullptr, bv, nullptr, 1.0f);
    // 4) scores[b] = Q[b] @ K[b]^T  (scale already in Q), fp16 out
    gemm_bt<2, 768, 768, 768><<<512, 512, 0, stream>>>(
        Qh, Kh, Sc, nullptr, nullptr, nullptr, 1.0f);
    // 5) P = softmax(scores) as fp16
    softmax_rows<<<32768, 256, 0, stream>>>(Sc, Ph);
    // 6) out[b] = P[b] @ V[b] == gemm_bt(P, V^T)
    gemm_bt<3, 1024, 1024, 1024><<<384, 512, 0, stream>>>(
        Ph, Vt, out, nullptr, nullptr, nullptr, 1.0f);
}